// Round 4
// baseline (204.003 us; speedup 1.0000x reference)
//
#include <hip/hip_runtime.h>

// Volume rendering: 2 rays per wave, 32 lanes per ray, 4 samples per lane.
// All cross-lane ops via DPP (VALU pipe, not LDS pipe).
// KEY FIX vs prev round: ROW_BCAST15 broadcasts lane15->row1, lane31->row2,
// lane47->row3. With 2 rays/wave the lane31->row2 write crosses the ray
// boundary and corrupts ray 1. row_mask=0xA (rows 1,3 only) confines the
// broadcast within each ray; masked rows keep `old` (identity).

#define N_SAMPLES 128

template <int CTRL, int ROWMASK = 0xf>
__device__ __forceinline__ float dpp_mov(float x, float oldv) {
    int r = __builtin_amdgcn_update_dpp(__float_as_int(oldv), __float_as_int(x),
                                        CTRL, ROWMASK, 0xf, false);
    return __int_as_float(r);
}

#define ROW_SHR1 0x111
#define ROW_SHR2 0x112
#define ROW_SHR4 0x114
#define ROW_SHR8 0x118
#define ROW_BCAST15 0x142
#define WAVE_SHL1 0x130
#define WAVE_SHR1 0x138

__global__ __launch_bounds__(256) void volrend_kernel(
    const float* __restrict__ rgb,      // (n_rays, 128, 3)
    const float* __restrict__ density,  // (n_rays, 128, 1)
    const float* __restrict__ z_vals,   // (n_rays, 128)
    const float* __restrict__ rays_d,   // (n_rays, 3)
    float* __restrict__ out_rgb,        // (n_rays, 3)
    float* __restrict__ out_depth,      // (n_rays,)
    float* __restrict__ out_w,          // (n_rays, 128)
    int n_rays)
{
    int tid    = blockIdx.x * blockDim.x + threadIdx.x;
    int wave   = tid >> 6;
    int lane   = threadIdx.x & 63;
    int ray    = wave * 2 + (lane >> 5);      // 2 rays per wave
    int lr     = lane & 31;                   // lane within ray
    if (ray >= n_rays) return;

    // ---- coalesced float4 loads: lane lr handles samples [4*lr, 4*lr+4) ----
    const float4* z4 = (const float4*)(z_vals  + (size_t)ray * N_SAMPLES);
    const float4* d4 = (const float4*)(density + (size_t)ray * N_SAMPLES);
    const float4* r4 = (const float4*)(rgb     + (size_t)ray * N_SAMPLES * 3);

    float4 z  = z4[lr];
    float4 dn = d4[lr];
    float4 r0 = r4[3 * lr + 0];   // s0.r s0.g s0.b s1.r
    float4 r1 = r4[3 * lr + 1];   // s1.g s1.b s2.r s2.g
    float4 r2 = r4[3 * lr + 2];   // s2.b s3.r s3.g s3.b

    float dx = rays_d[ray * 3 + 0];
    float dy = rays_d[ray * 3 + 1];
    float dz = rays_d[ray * 3 + 2];
    float nrm = sqrtf(dx * dx + dy * dy + dz * dz);

    // ---- dists: need z.x of next lane (lane i <- lane i+1 via wave_shl1) ----
    float znext = dpp_mov<WAVE_SHL1>(z.x, 0.0f);
    bool last = (lr == 31);                   // lane 31 reads lane 32 (other
                                              // ray) but 'last' path ignores it
    float dist0 = (z.y - z.x) * nrm;
    float dist1 = (z.z - z.y) * nrm;
    float dist2 = (z.w - z.z) * nrm;
    float dist3 = last ? (1e10f * nrm) : ((znext - z.w) * nrm);

    // ---- alpha / survival probability ----
    float e0 = __expf(-fmaxf(dn.x, 0.0f) * dist0);
    float e1 = __expf(-fmaxf(dn.y, 0.0f) * dist1);
    float e2 = __expf(-fmaxf(dn.z, 0.0f) * dist2);
    float e3 = __expf(-fmaxf(dn.w, 0.0f) * dist3);
    float a0 = 1.0f - e0, a1 = 1.0f - e1, a2 = 1.0f - e2, a3 = 1.0f - e3;
    float p0 = e0 + 1e-10f, p1 = e1 + 1e-10f, p2 = e2 + 1e-10f, p3 = e3 + 1e-10f;

    // ---- exclusive prefix product of p across the 32 lanes of this ray ----
    float x = p0 * p1 * p2 * p3;                  // per-lane product
    x *= dpp_mov<ROW_SHR1>(x, 1.0f);              // row-local (16-lane) steps
    x *= dpp_mov<ROW_SHR2>(x, 1.0f);
    x *= dpp_mov<ROW_SHR4>(x, 1.0f);
    x *= dpp_mov<ROW_SHR8>(x, 1.0f);
    // cross 16-lane boundary WITHIN each ray only: rows 1 and 3 (mask 0xA).
    x *= dpp_mov<ROW_BCAST15, 0xA>(x, 1.0f);
    float ex = dpp_mov<WAVE_SHR1>(x, 1.0f);       // exclusive shift
    if (lr == 0) ex = 1.0f;                        // first lane of each ray
                                                   // (also kills lane32<-31)

    // ---- per-sample transmittance & weights ----
    float T0 = ex;
    float T1 = T0 * p0;
    float T2 = T1 * p1;
    float T3 = T2 * p2;
    float w0 = a0 * T0, w1 = a1 * T1, w2 = a2 * T2, w3 = a3 * T3;

    // ---- coalesced weights store ----
    ((float4*)(out_w + (size_t)ray * N_SAMPLES))[lr] = make_float4(w0, w1, w2, w3);

    // ---- per-lane weighted partial sums ----
    float cr = w0 * r0.x + w1 * r0.w + w2 * r1.z + w3 * r2.y;
    float cg = w0 * r0.y + w1 * r1.x + w2 * r1.w + w3 * r2.z;
    float cb = w0 * r0.z + w1 * r1.y + w2 * r2.x + w3 * r2.w;
    float cd = w0 * z.x  + w1 * z.y  + w2 * z.z  + w3 * z.w;

    // ---- reduce across the 32 lanes of each ray; total lands in lane 31/63.
    // row_shr accumulates toward higher lanes; masked bcast15 (rows 1,3)
    // carries row totals across the 16-lane boundary within each ray.
    cr += dpp_mov<ROW_SHR1>(cr, 0.0f);
    cg += dpp_mov<ROW_SHR1>(cg, 0.0f);
    cb += dpp_mov<ROW_SHR1>(cb, 0.0f);
    cd += dpp_mov<ROW_SHR1>(cd, 0.0f);
    cr += dpp_mov<ROW_SHR2>(cr, 0.0f);
    cg += dpp_mov<ROW_SHR2>(cg, 0.0f);
    cb += dpp_mov<ROW_SHR2>(cb, 0.0f);
    cd += dpp_mov<ROW_SHR2>(cd, 0.0f);
    cr += dpp_mov<ROW_SHR4>(cr, 0.0f);
    cg += dpp_mov<ROW_SHR4>(cg, 0.0f);
    cb += dpp_mov<ROW_SHR4>(cb, 0.0f);
    cd += dpp_mov<ROW_SHR4>(cd, 0.0f);
    cr += dpp_mov<ROW_SHR8>(cr, 0.0f);
    cg += dpp_mov<ROW_SHR8>(cg, 0.0f);
    cb += dpp_mov<ROW_SHR8>(cb, 0.0f);
    cd += dpp_mov<ROW_SHR8>(cd, 0.0f);
    cr += dpp_mov<ROW_BCAST15, 0xA>(cr, 0.0f);
    cg += dpp_mov<ROW_BCAST15, 0xA>(cg, 0.0f);
    cb += dpp_mov<ROW_BCAST15, 0xA>(cb, 0.0f);
    cd += dpp_mov<ROW_BCAST15, 0xA>(cd, 0.0f);

    if (lr == 31) {
        out_rgb[ray * 3 + 0] = cr;
        out_rgb[ray * 3 + 1] = cg;
        out_rgb[ray * 3 + 2] = cb;
        out_depth[ray] = cd;
    }
}

extern "C" void kernel_launch(void* const* d_in, const int* in_sizes, int n_in,
                              void* d_out, int out_size, void* d_ws, size_t ws_size,
                              hipStream_t stream) {
    const float* rgb     = (const float*)d_in[0];
    const float* density = (const float*)d_in[1];
    const float* z_vals  = (const float*)d_in[2];
    const float* rays_d  = (const float*)d_in[3];

    int n_rays = in_sizes[3] / 3;   // rays_d is (n_rays, 3)

    float* out       = (float*)d_out;
    float* out_rgb   = out;                          // n_rays*3
    float* out_depth = out + (size_t)n_rays * 3;     // n_rays
    float* out_w     = out_depth + n_rays;           // n_rays*128

    int block = 256;                 // 4 waves = 8 rays per block
    int rays_per_block = (block / 64) * 2;
    int grid = (n_rays + rays_per_block - 1) / rays_per_block;
    volrend_kernel<<<grid, block, 0, stream>>>(rgb, density, z_vals, rays_d,
                                               out_rgb, out_depth, out_w, n_rays);
}

// Round 5
// 202.974 us; speedup vs baseline: 1.0051x; 1.0051x over previous
//
#include <hip/hip_runtime.h>

// Volume rendering: 2 rays per wave (32 lanes/ray, 4 samples/lane), DPP
// cross-lane ops, and a software-pipelined loop: each wave processes ITERS
// ray-pairs with register double-buffering so the loads of pair i+1 are in
// flight while the compute tail (exp + DPP chains) of pair i runs. This keeps
// memory requests continuously outstanding instead of the burst-then-stall
// pattern that left every pipe <25% busy in rounds 2-4.

#define N_SAMPLES 128
#define ITERS 4

template <int CTRL, int ROWMASK = 0xf>
__device__ __forceinline__ float dpp_mov(float x, float oldv) {
    int r = __builtin_amdgcn_update_dpp(__float_as_int(oldv), __float_as_int(x),
                                        CTRL, ROWMASK, 0xf, false);
    return __int_as_float(r);
}

#define ROW_SHR1 0x111
#define ROW_SHR2 0x112
#define ROW_SHR4 0x114
#define ROW_SHR8 0x118
#define ROW_BCAST15 0x142
#define WAVE_SHL1 0x130
#define WAVE_SHR1 0x138

struct Frag {
    float4 z, dn, r0, r1, r2;
    float nx, ny, nz;
};

__device__ __forceinline__ void load_frag(Frag& f,
    const float* __restrict__ rgb, const float* __restrict__ density,
    const float* __restrict__ z_vals, const float* __restrict__ rays_d,
    int ray, int lr)
{
    const float4* z4 = (const float4*)(z_vals  + (size_t)ray * N_SAMPLES);
    const float4* d4 = (const float4*)(density + (size_t)ray * N_SAMPLES);
    const float4* r4 = (const float4*)(rgb     + (size_t)ray * N_SAMPLES * 3);
    f.z  = z4[lr];
    f.dn = d4[lr];
    f.r0 = r4[3 * lr + 0];   // s0.r s0.g s0.b s1.r
    f.r1 = r4[3 * lr + 1];   // s1.g s1.b s2.r s2.g
    f.r2 = r4[3 * lr + 2];   // s2.b s3.r s3.g s3.b
    f.nx = rays_d[ray * 3 + 0];
    f.ny = rays_d[ray * 3 + 1];
    f.nz = rays_d[ray * 3 + 2];
}

__device__ __forceinline__ void compute_frag(const Frag& f, int ray, int lr,
    float* __restrict__ out_rgb, float* __restrict__ out_depth,
    float* __restrict__ out_w)
{
    float nrm = sqrtf(f.nx * f.nx + f.ny * f.ny + f.nz * f.nz);

    // dists: z.x of next lane (lane i <- lane i+1)
    float znext = dpp_mov<WAVE_SHL1>(f.z.x, 0.0f);
    bool last = (lr == 31);
    float dist0 = (f.z.y - f.z.x) * nrm;
    float dist1 = (f.z.z - f.z.y) * nrm;
    float dist2 = (f.z.w - f.z.z) * nrm;
    float dist3 = last ? (1e10f * nrm) : ((znext - f.z.w) * nrm);

    float e0 = __expf(-fmaxf(f.dn.x, 0.0f) * dist0);
    float e1 = __expf(-fmaxf(f.dn.y, 0.0f) * dist1);
    float e2 = __expf(-fmaxf(f.dn.z, 0.0f) * dist2);
    float e3 = __expf(-fmaxf(f.dn.w, 0.0f) * dist3);
    float a0 = 1.0f - e0, a1 = 1.0f - e1, a2 = 1.0f - e2, a3 = 1.0f - e3;
    float p0 = e0 + 1e-10f, p1 = e1 + 1e-10f, p2 = e2 + 1e-10f, p3 = e3 + 1e-10f;

    // exclusive prefix product across the 32 lanes of this ray.
    // ROW_BCAST15 with row_mask=0xA stays within each ray (see round-3 fix).
    float x = p0 * p1 * p2 * p3;
    x *= dpp_mov<ROW_SHR1>(x, 1.0f);
    x *= dpp_mov<ROW_SHR2>(x, 1.0f);
    x *= dpp_mov<ROW_SHR4>(x, 1.0f);
    x *= dpp_mov<ROW_SHR8>(x, 1.0f);
    x *= dpp_mov<ROW_BCAST15, 0xA>(x, 1.0f);
    float ex = dpp_mov<WAVE_SHR1>(x, 1.0f);
    if (lr == 0) ex = 1.0f;

    float T0 = ex;
    float T1 = T0 * p0;
    float T2 = T1 * p1;
    float T3 = T2 * p2;
    float w0 = a0 * T0, w1 = a1 * T1, w2 = a2 * T2, w3 = a3 * T3;

    ((float4*)(out_w + (size_t)ray * N_SAMPLES))[lr] = make_float4(w0, w1, w2, w3);

    float cr = w0 * f.r0.x + w1 * f.r0.w + w2 * f.r1.z + w3 * f.r2.y;
    float cg = w0 * f.r0.y + w1 * f.r1.x + w2 * f.r1.w + w3 * f.r2.z;
    float cb = w0 * f.r0.z + w1 * f.r1.y + w2 * f.r2.x + w3 * f.r2.w;
    float cd = w0 * f.z.x  + w1 * f.z.y  + w2 * f.z.z  + w3 * f.z.w;

    cr += dpp_mov<ROW_SHR1>(cr, 0.0f);
    cg += dpp_mov<ROW_SHR1>(cg, 0.0f);
    cb += dpp_mov<ROW_SHR1>(cb, 0.0f);
    cd += dpp_mov<ROW_SHR1>(cd, 0.0f);
    cr += dpp_mov<ROW_SHR2>(cr, 0.0f);
    cg += dpp_mov<ROW_SHR2>(cg, 0.0f);
    cb += dpp_mov<ROW_SHR2>(cb, 0.0f);
    cd += dpp_mov<ROW_SHR2>(cd, 0.0f);
    cr += dpp_mov<ROW_SHR4>(cr, 0.0f);
    cg += dpp_mov<ROW_SHR4>(cg, 0.0f);
    cb += dpp_mov<ROW_SHR4>(cb, 0.0f);
    cd += dpp_mov<ROW_SHR4>(cd, 0.0f);
    cr += dpp_mov<ROW_SHR8>(cr, 0.0f);
    cg += dpp_mov<ROW_SHR8>(cg, 0.0f);
    cb += dpp_mov<ROW_SHR8>(cb, 0.0f);
    cd += dpp_mov<ROW_SHR8>(cd, 0.0f);
    cr += dpp_mov<ROW_BCAST15, 0xA>(cr, 0.0f);
    cg += dpp_mov<ROW_BCAST15, 0xA>(cg, 0.0f);
    cb += dpp_mov<ROW_BCAST15, 0xA>(cb, 0.0f);
    cd += dpp_mov<ROW_BCAST15, 0xA>(cd, 0.0f);

    if (lr == 31) {
        out_rgb[ray * 3 + 0] = cr;
        out_rgb[ray * 3 + 1] = cg;
        out_rgb[ray * 3 + 2] = cb;
        out_depth[ray] = cd;
    }
}

__global__ __launch_bounds__(256) void volrend_kernel(
    const float* __restrict__ rgb,      // (n_rays, 128, 3)
    const float* __restrict__ density,  // (n_rays, 128, 1)
    const float* __restrict__ z_vals,   // (n_rays, 128)
    const float* __restrict__ rays_d,   // (n_rays, 3)
    float* __restrict__ out_rgb,        // (n_rays, 3)
    float* __restrict__ out_depth,      // (n_rays,)
    float* __restrict__ out_w,          // (n_rays, 128)
    int n_rays, int n_waves)
{
    int tid  = blockIdx.x * blockDim.x + threadIdx.x;
    int wid  = tid >> 6;
    int lane = threadIdx.x & 63;
    int lr   = lane & 31;
    int half = lane >> 5;

    int n_pairs = (n_rays + 1) >> 1;

    int pair = wid;
    Frag f[2];

    // prologue: prefetch pair 0
    {
        int ray = pair * 2 + half;
        if (pair < n_pairs && ray < n_rays)
            load_frag(f[0], rgb, density, z_vals, rays_d, ray, lr);
    }

    #pragma unroll
    for (int i = 0; i < ITERS; ++i) {
        int buf = i & 1;
        int npair = pair + n_waves;
        // issue next pair's loads BEFORE computing current pair
        if (i + 1 < ITERS) {
            int nray = npair * 2 + half;
            if (npair < n_pairs && nray < n_rays)
                load_frag(f[buf ^ 1], rgb, density, z_vals, rays_d, nray, lr);
        }
        int ray = pair * 2 + half;
        if (pair < n_pairs && ray < n_rays)
            compute_frag(f[buf], ray, lr, out_rgb, out_depth, out_w);
        pair = npair;
    }
}

extern "C" void kernel_launch(void* const* d_in, const int* in_sizes, int n_in,
                              void* d_out, int out_size, void* d_ws, size_t ws_size,
                              hipStream_t stream) {
    const float* rgb     = (const float*)d_in[0];
    const float* density = (const float*)d_in[1];
    const float* z_vals  = (const float*)d_in[2];
    const float* rays_d  = (const float*)d_in[3];

    int n_rays = in_sizes[3] / 3;   // rays_d is (n_rays, 3)

    float* out       = (float*)d_out;
    float* out_rgb   = out;                          // n_rays*3
    float* out_depth = out + (size_t)n_rays * 3;     // n_rays
    float* out_w     = out_depth + n_rays;           // n_rays*128

    int block = 256;                       // 4 waves/block
    int waves_per_block = block / 64;
    int n_pairs = (n_rays + 1) / 2;
    int total_waves = (n_pairs + ITERS - 1) / ITERS;
    int grid = (total_waves + waves_per_block - 1) / waves_per_block;
    int n_waves = grid * waves_per_block;  // pair stride per iteration

    volrend_kernel<<<grid, block, 0, stream>>>(rgb, density, z_vals, rays_d,
                                               out_rgb, out_depth, out_w,
                                               n_rays, n_waves);
}